// Round 14
// baseline (73.914 us; speedup 1.0000x reference)
//
#include <hip/hip_runtime.h>

#define EPSF 1e-6f
#define L2E  1.44269504088896340736f   // log2(e)

using bf16x8 = __attribute__((ext_vector_type(8))) short;  // 8 bf16 (4 VGPRs)
using f32x16 = __attribute__((ext_vector_type(16))) float;

constexpr int NT   = 256;
constexpr int JC   = 512;               // q columns per block
constexpr int NJC  = 8192 / JC;         // 16 chunks
constexpr int RPAN = 128;               // z rows per block (4 waves x 32)
constexpr int NRP  = 16384 / RPAN;      // 128 row panels
constexpr int NB   = NRP * NJC;         // 2048 blocks (8/CU)
constexpr int JT   = JC / 32;           // 16 j-tiles per chunk

// RNE float -> bf16 (as short), and back
__device__ __forceinline__ short f2bf(float f) {
    union { float f; unsigned u; } c{f};
    return (short)((c.u + 0x7fffu + ((c.u >> 16) & 1u)) >> 16);
}
__device__ __forceinline__ float bf2f(short s) {
    union { unsigned u; float f; } c{((unsigned)(unsigned short)s) << 16};
    return c.f;
}

// ---------------------------------------------------------------------------
__device__ __forceinline__ float block_reduce_sum(float v) {
#pragma unroll
    for (int off = 32; off > 0; off >>= 1) v += __shfl_down(v, off, 64);
    __shared__ float parts[4];
    const int t = threadIdx.x;
    if ((t & 63) == 0) parts[t >> 6] = v;
    __syncthreads();
    float r = 0.f;
    if (t == 0) r = parts[0] + parts[1] + parts[2] + parts[3];
    return r;
}

// Augmented A-frag for one z row straight from global (L2-resident).
// half 0: [zh_0..zh_7]; half 1: [zn, 1, 0...]  (zh = bf16(L2E*(z+eps)))
__device__ __forceinline__ bf16x8 make_afrag(const float* __restrict__ z,
                                             int row, int half) {
    const float4 a = *(const float4*)(z + (size_t)row * 8);
    const float4 b = *(const float4*)(z + (size_t)row * 8 + 4);
    const float h[8] = {L2E * (a.x + EPSF), L2E * (a.y + EPSF),
                        L2E * (a.z + EPSF), L2E * (a.w + EPSF),
                        L2E * (b.x + EPSF), L2E * (b.y + EPSF),
                        L2E * (b.z + EPSF), L2E * (b.w + EPSF)};
    short s[8];
    float zn = 0.f;
#pragma unroll
    for (int d = 0; d < 8; ++d) {
        s[d] = f2bf(h[d]);
        const float r = bf2f(s[d]);
        zn = fmaf(r, r, zn);
    }
    bf16x8 f;
    if (half == 0) {
        f[0] = s[0]; f[1] = s[1]; f[2] = s[2]; f[3] = s[3];
        f[4] = s[4]; f[5] = s[5]; f[6] = s[6]; f[7] = s[7];
    } else {
        f[0] = f2bf(zn); f[1] = (short)0x3F80;
        f[2] = 0; f[3] = 0; f[4] = 0; f[5] = 0; f[6] = 0; f[7] = 0;
    }
    return f;
}

// ---------------------------------------------------------------------------
__device__ __forceinline__ float sparse_slice(
    const float* __restrict__ z, const float* __restrict__ q,
    const float* __restrict__ gamma, const float* __restrict__ delta,
    const float* __restrict__ w, const int* __restrict__ si,
    const int* __restrict__ sj, int nnz, int k0)
{
    float sacc = 0.f;
    for (int k = k0; k < nnz; k += NB * NT) {
        const int i = si[k];
        const int j = sj[k];
        const float4 a = *(const float4*)(z + (size_t)i * 8);
        const float4 b = *(const float4*)(z + (size_t)i * 8 + 4);
        const float4 c = *(const float4*)(q + (size_t)j * 8);
        const float4 d = *(const float4*)(q + (size_t)j * 8 + 4);
        const float d0 = a.x - c.x + EPSF, d1 = a.y - c.y + EPSF;
        const float d2 = a.z - c.z + EPSF, d3 = a.w - c.w + EPSF;
        const float d4 = b.x - d.x + EPSF, d5 = b.y - d.y + EPSF;
        const float d6 = b.z - d.z + EPSF, d7 = b.w - d.w + EPSF;
        float s2 = d0 * d0;
        s2 = fmaf(d1, d1, s2); s2 = fmaf(d2, d2, s2); s2 = fmaf(d3, d3, s2);
        s2 = fmaf(d4, d4, s2); s2 = fmaf(d5, d5, s2); s2 = fmaf(d6, d6, s2);
        s2 = fmaf(d7, d7, s2);
        sacc = fmaf(w[k], gamma[i] + delta[j] - __builtin_amdgcn_sqrtf(s2), sacc);
    }
    return sacc;
}

// ---------------------------------------------------------------------------
// Dense: K=10 augmented 32x32x16 MFMA emits D = L2E^2*dist^2 directly.
//   A row i = [zh, zn_i, 1, 0...] ; B col j = [-2qh, 1, qn_j, 0...]
//   term = ed_j * 2^(-sqrt(D)), ed = exp(delta-eps); weight exp(gamma_i) last.
// B in split 16B granule pools (conflict-free b128 at imm offsets).
// Blocks phase-staggered by (id>>8)&1: group A = sparse->bar->dense,
// group B = bar->dense->fence->sparse, so co-resident blocks keep both the
// trans pipe and the memory system busy.  The fence (memory clobber) is what
// r12 lacked - it stops gather hoisting into the MFMA epilogue (spill guard).
// ---------------------------------------------------------------------------
__global__ __launch_bounds__(NT) void fused_kernel(
    const float* __restrict__ z, const float* __restrict__ q,
    const float* __restrict__ gamma, const float* __restrict__ delta,
    const float* __restrict__ w, const int* __restrict__ si,
    const int* __restrict__ sj, int nnz, float* __restrict__ partial)
{
    __shared__ __align__(16) short sqb[1024 * 8];  // 16KB B granules
    __shared__ float sed[JC];                      // 2KB  exp(delta - eps)
    __shared__ float seg[RPAN];                    // 512B exp(gamma)

    const int t    = threadIdx.x;
    const int id   = blockIdx.x;
    const int jc   = id & (NJC - 1);
    const int rpan = id >> 4;            // id / NJC
    const int c0   = jc * JC;
    const int r0   = rpan * RPAN;

    if (t < RPAN) seg[t] = __expf(gamma[r0 + t]);

    // ---- stage B cols (2 per thread) into granule pools ----
#pragma unroll
    for (int c = t; c < JC; c += NT) {
        const int C = c0 + c;
        const float4 a = *(const float4*)(q + (size_t)C * 8);
        const float4 b = *(const float4*)(q + (size_t)C * 8 + 4);
        const float h[8] = {L2E * a.x, L2E * a.y, L2E * a.z, L2E * a.w,
                            L2E * b.x, L2E * b.y, L2E * b.z, L2E * b.w};
        bf16x8 g0;
        float qn = 0.f;
#pragma unroll
        for (int d = 0; d < 8; ++d) {
            const short s = f2bf(h[d]);
            const float r = bf2f(s);
            qn = fmaf(r, r, qn);
            g0[d] = f2bf(-2.f * r);      // exact: -2x is exponent bump + sign
        }
        *(bf16x8*)&sqb[c * 8] = g0;
        bf16x8 g1;
        g1[0] = (short)0x3F80;           // 1.0 bf16
        g1[1] = f2bf(qn);
        g1[2] = 0; g1[3] = 0; g1[4] = 0; g1[5] = 0; g1[6] = 0; g1[7] = 0;
        *(bf16x8*)&sqb[(512 + c) * 8] = g1;
        sed[c] = __expf(delta[C] - EPSF);
    }

    // ---- A-frag per lane (only 4 VGPRs live across sparse) ----
    const int wv   = t >> 6;
    const int lane = t & 63;
    const int li   = lane & 31;
    const int half = lane >> 5;
    const bf16x8 afrag = make_afrag(z, r0 + wv * 32 + li, half);

    const int  k0     = id * NT + t;
    const bool sparse_first = ((id >> 8) & 1) == 0;

    float sacc = 0.f;
    if (sparse_first) {
        sacc = sparse_slice(z, q, gamma, delta, w, si, sj, nnz, k0);
    }
    __syncthreads();

    // ---- dense: 16 j-tiles, conflict-free b128 reads at imm offsets ----
    const short* bbase = &sqb[(half * 512 + li) * 8];
    const float* edp   = &sed[li];

    float acc[16];
#pragma unroll
    for (int r = 0; r < 16; ++r) acc[r] = 0.f;

#pragma unroll
    for (int jt = 0; jt < JT; ++jt) {
        const bf16x8 bfrag = *(const bf16x8*)(bbase + jt * 32 * 8);
        const float  ed_l  = edp[jt * 32];
        f32x16 s = __builtin_amdgcn_mfma_f32_32x32x16_bf16(
            afrag, bfrag, (f32x16)(0.f), 0, 0, 0);
#pragma unroll
        for (int r = 0; r < 16; ++r) {
            const float st = __builtin_amdgcn_sqrtf(__builtin_fabsf(s[r]));
            acc[r] = fmaf(ed_l, __builtin_amdgcn_exp2f(-st), acc[r]);
        }
    }

    // weight by exp(gamma_row); row = wv*32 + 4*half + (r&3) + 8*(r>>2)
    float vv = 0.f;
#pragma unroll
    for (int r4 = 0; r4 < 4; ++r4)
#pragma unroll
        for (int rr = 0; rr < 4; ++rr)
            vv = fmaf(seg[wv * 32 + half * 4 + rr + 8 * r4], acc[r4 * 4 + rr], vv);

    if (!sparse_first) {
        // fence: keep the gather loop strictly after the dense epilogue
        __builtin_amdgcn_sched_barrier(0);
        asm volatile("" ::: "memory");
        sacc = sparse_slice(z, q, gamma, delta, w, si, sj, nnz, k0);
    }

    const float v = block_reduce_sum(sacc - vv);
    if (t == 0) partial[id] = v;
}

// ---------------------------------------------------------------------------
__global__ __launch_bounds__(256) void reduce_kernel(
    const float* __restrict__ partial, int n, float* __restrict__ out)
{
    float v = 0.f;
    for (int k = threadIdx.x; k < n; k += 256) v += partial[k];
    v = block_reduce_sum(v);
    if (threadIdx.x == 0) out[0] = v;
}

// ---------------------------------------------------------------------------
extern "C" void kernel_launch(void* const* d_in, const int* in_sizes, int n_in,
                              void* d_out, int out_size, void* d_ws, size_t ws_size,
                              hipStream_t stream) {
    const float* z     = (const float*)d_in[0];   // [16384, 8]
    const float* q     = (const float*)d_in[1];   // [8192, 8]
    const float* gamma = (const float*)d_in[2];   // [16384]
    const float* delta = (const float*)d_in[3];   // [8192]
    const float* w     = (const float*)d_in[4];   // [nnz]
    const int*   si    = (const int*)d_in[5];     // [nnz]
    const int*   sj    = (const int*)d_in[6];     // [nnz]
    const int    nnz   = in_sizes[4];

    float* out = (float*)d_out;
    float* ws  = (float*)d_ws;

    fused_kernel<<<NB, NT, 0, stream>>>(z, q, gamma, delta, w, si, sj, nnz, ws);
    reduce_kernel<<<1, 256, 0, stream>>>(ws, NB, out);
}

// Round 15
// 41.987 us; speedup vs baseline: 1.7604x; 1.7604x over previous
//
#include <hip/hip_runtime.h>

#define EPSF 1e-6f
#define L2E  1.44269504088896340736f   // log2(e)

using bf16x8 = __attribute__((ext_vector_type(8))) short;  // 8 bf16 (4 VGPRs)
using f32x16 = __attribute__((ext_vector_type(16))) float;

constexpr int NT   = 256;
constexpr int JC   = 512;               // q columns per dense block
constexpr int NJC  = 8192 / JC;         // 16 chunks
constexpr int RPAN = 128;               // z rows per dense block (4 waves x 32)
constexpr int NRP  = 16384 / RPAN;      // 128 row panels
constexpr int ND   = NRP * NJC;         // 2048 dense blocks (8/CU)
constexpr int NS   = 256;               // sparse blocks (1/CU, resident from t=0)
constexpr int NB   = NS + ND;           // 2304 total
constexpr int JT   = JC / 32;           // 16 j-tiles per chunk

// RNE float -> bf16 (as short), and back
__device__ __forceinline__ short f2bf(float f) {
    union { float f; unsigned u; } c{f};
    return (short)((c.u + 0x7fffu + ((c.u >> 16) & 1u)) >> 16);
}
__device__ __forceinline__ float bf2f(short s) {
    union { unsigned u; float f; } c{((unsigned)(unsigned short)s) << 16};
    return c.f;
}

// ---------------------------------------------------------------------------
__device__ __forceinline__ float block_reduce_sum(float v) {
#pragma unroll
    for (int off = 32; off > 0; off >>= 1) v += __shfl_down(v, off, 64);
    __shared__ float parts[4];
    const int t = threadIdx.x;
    if ((t & 63) == 0) parts[t >> 6] = v;
    __syncthreads();
    float r = 0.f;
    if (t == 0) r = parts[0] + parts[1] + parts[2] + parts[3];
    return r;
}

// Augmented A-frag for one z row straight from global (L2-resident).
// half 0: [zh_0..zh_7]; half 1: [zn, 1, 0...]  (zh = bf16(L2E*(z+eps)))
__device__ __forceinline__ bf16x8 make_afrag(const float* __restrict__ z,
                                             int row, int half) {
    const float4 a = *(const float4*)(z + (size_t)row * 8);
    const float4 b = *(const float4*)(z + (size_t)row * 8 + 4);
    const float h[8] = {L2E * (a.x + EPSF), L2E * (a.y + EPSF),
                        L2E * (a.z + EPSF), L2E * (a.w + EPSF),
                        L2E * (b.x + EPSF), L2E * (b.y + EPSF),
                        L2E * (b.z + EPSF), L2E * (b.w + EPSF)};
    short s[8];
    float zn = 0.f;
#pragma unroll
    for (int d = 0; d < 8; ++d) {
        s[d] = f2bf(h[d]);
        const float r = bf2f(s[d]);
        zn = fmaf(r, r, zn);
    }
    bf16x8 f;
    if (half == 0) {
        f[0] = s[0]; f[1] = s[1]; f[2] = s[2]; f[3] = s[3];
        f[4] = s[4]; f[5] = s[5]; f[6] = s[6]; f[7] = s[7];
    } else {
        f[0] = f2bf(zn); f[1] = (short)0x3F80;
        f[2] = 0; f[3] = 0; f[4] = 0; f[5] = 0; f[6] = 0; f[7] = 0;
    }
    return f;
}

// ---------------------------------------------------------------------------
// Block-specialized: ids [0,NS) do the sparse Poisson term (pure gather, one
// block per CU, resident from t=0); ids [NS,NB) are pure-dense MFMA blocks
// (stage -> barrier -> 16 tiles).  Dense/sparse overlap at CU level, so no
// per-block gather->barrier convoy, and the two paths are register-disjoint
// (the r14 lesson: a dense+sparse path union blows VGPR).
// Dense: K=10 augmented 32x32x16 MFMA emits D = L2E^2*dist^2 directly.
//   A row i = [zh, zn_i, 1, 0...] ; B col j = [-2qh, 1, qn_j, 0...]
//   term = ed_j * 2^(-sqrt(D)), ed = exp(delta-eps); weight exp(gamma_i) last.
// ---------------------------------------------------------------------------
__global__ __launch_bounds__(NT) void fused_kernel(
    const float* __restrict__ z, const float* __restrict__ q,
    const float* __restrict__ gamma, const float* __restrict__ delta,
    const float* __restrict__ w, const int* __restrict__ si,
    const int* __restrict__ sj, int nnz, float* __restrict__ partial)
{
    __shared__ __align__(16) short sqb[1024 * 8];  // 16KB B granules
    __shared__ float sed[JC];                      // 2KB  exp(delta - eps)
    __shared__ float seg[RPAN];                    // 512B exp(gamma)

    const int t  = threadIdx.x;
    const int id = blockIdx.x;

    if (id < NS) {
        // ---------------- sparse path (pure gather) ----------------
        float sacc = 0.f;
        for (int k = id * NT + t; k < nnz; k += NS * NT) {
            const int i = si[k];
            const int j = sj[k];
            const float4 a = *(const float4*)(z + (size_t)i * 8);
            const float4 b = *(const float4*)(z + (size_t)i * 8 + 4);
            const float4 c = *(const float4*)(q + (size_t)j * 8);
            const float4 d = *(const float4*)(q + (size_t)j * 8 + 4);
            const float d0 = a.x - c.x + EPSF, d1 = a.y - c.y + EPSF;
            const float d2 = a.z - c.z + EPSF, d3 = a.w - c.w + EPSF;
            const float d4 = b.x - d.x + EPSF, d5 = b.y - d.y + EPSF;
            const float d6 = b.z - d.z + EPSF, d7 = b.w - d.w + EPSF;
            float s2 = d0 * d0;
            s2 = fmaf(d1, d1, s2); s2 = fmaf(d2, d2, s2); s2 = fmaf(d3, d3, s2);
            s2 = fmaf(d4, d4, s2); s2 = fmaf(d5, d5, s2); s2 = fmaf(d6, d6, s2);
            s2 = fmaf(d7, d7, s2);
            sacc = fmaf(w[k], gamma[i] + delta[j] - __builtin_amdgcn_sqrtf(s2), sacc);
        }
        const float v = block_reduce_sum(sacc);
        if (t == 0) partial[id] = v;
        return;
    }

    // ---------------- dense path (pure MFMA) ----------------
    const int did  = id - NS;
    const int jc   = did & (NJC - 1);
    const int rpan = did >> 4;           // did / NJC
    const int c0   = jc * JC;
    const int r0   = rpan * RPAN;

    if (t < RPAN) seg[t] = __expf(gamma[r0 + t]);

    // stage B cols (2 per thread) into split granule pools
#pragma unroll
    for (int c = t; c < JC; c += NT) {
        const int C = c0 + c;
        const float4 a = *(const float4*)(q + (size_t)C * 8);
        const float4 b = *(const float4*)(q + (size_t)C * 8 + 4);
        const float h[8] = {L2E * a.x, L2E * a.y, L2E * a.z, L2E * a.w,
                            L2E * b.x, L2E * b.y, L2E * b.z, L2E * b.w};
        bf16x8 g0;
        float qn = 0.f;
#pragma unroll
        for (int d = 0; d < 8; ++d) {
            const short s = f2bf(h[d]);
            const float r = bf2f(s);
            qn = fmaf(r, r, qn);
            g0[d] = f2bf(-2.f * r);      // exact: -2x is exponent bump + sign
        }
        *(bf16x8*)&sqb[c * 8] = g0;
        bf16x8 g1;
        g1[0] = (short)0x3F80;           // 1.0 bf16
        g1[1] = f2bf(qn);
        g1[2] = 0; g1[3] = 0; g1[4] = 0; g1[5] = 0; g1[6] = 0; g1[7] = 0;
        *(bf16x8*)&sqb[(512 + c) * 8] = g1;
        sed[c] = __expf(delta[C] - EPSF);
    }

    const int wv   = t >> 6;
    const int lane = t & 63;
    const int li   = lane & 31;
    const int half = lane >> 5;
    const bf16x8 afrag = make_afrag(z, r0 + wv * 32 + li, half);

    __syncthreads();

    const short* bbase = &sqb[(half * 512 + li) * 8];
    const float* edp   = &sed[li];

    float acc[16];
#pragma unroll
    for (int r = 0; r < 16; ++r) acc[r] = 0.f;

#pragma unroll
    for (int jt = 0; jt < JT; ++jt) {
        const bf16x8 bfrag = *(const bf16x8*)(bbase + jt * 32 * 8);
        const float  ed_l  = edp[jt * 32];
        f32x16 s = __builtin_amdgcn_mfma_f32_32x32x16_bf16(
            afrag, bfrag, (f32x16)(0.f), 0, 0, 0);
#pragma unroll
        for (int r = 0; r < 16; ++r) {
            const float st = __builtin_amdgcn_sqrtf(__builtin_fabsf(s[r]));
            acc[r] = fmaf(ed_l, __builtin_amdgcn_exp2f(-st), acc[r]);
        }
    }

    // weight by exp(gamma_row); row = wv*32 + 4*half + (r&3) + 8*(r>>2)
    float vv = 0.f;
#pragma unroll
    for (int r4 = 0; r4 < 4; ++r4)
#pragma unroll
        for (int rr = 0; rr < 4; ++rr)
            vv = fmaf(seg[wv * 32 + half * 4 + rr + 8 * r4], acc[r4 * 4 + rr], vv);

    const float v = block_reduce_sum(-vv);
    if (t == 0) partial[id] = v;
}

// ---------------------------------------------------------------------------
__global__ __launch_bounds__(256) void reduce_kernel(
    const float* __restrict__ partial, int n, float* __restrict__ out)
{
    float v = 0.f;
    for (int k = threadIdx.x; k < n; k += 256) v += partial[k];
    v = block_reduce_sum(v);
    if (threadIdx.x == 0) out[0] = v;
}

// ---------------------------------------------------------------------------
extern "C" void kernel_launch(void* const* d_in, const int* in_sizes, int n_in,
                              void* d_out, int out_size, void* d_ws, size_t ws_size,
                              hipStream_t stream) {
    const float* z     = (const float*)d_in[0];   // [16384, 8]
    const float* q     = (const float*)d_in[1];   // [8192, 8]
    const float* gamma = (const float*)d_in[2];   // [16384]
    const float* delta = (const float*)d_in[3];   // [8192]
    const float* w     = (const float*)d_in[4];   // [nnz]
    const int*   si    = (const int*)d_in[5];     // [nnz]
    const int*   sj    = (const int*)d_in[6];     // [nnz]
    const int    nnz   = in_sizes[4];

    float* out = (float*)d_out;
    float* ws  = (float*)d_ws;

    fused_kernel<<<NB, NT, 0, stream>>>(z, q, gamma, delta, w, si, sj, nnz, ws);
    reduce_kernel<<<1, 256, 0, stream>>>(ws, NB, out);
}